// Round 11
// baseline (528.281 us; speedup 1.0000x reference)
//
#include <hip/hip_runtime.h>

typedef float v4f __attribute__((ext_vector_type(4)));

namespace {
constexpr int B_     = 8;
constexpr int NT_    = 256;
constexpr int NX_    = 256;
constexpr int NREC_  = 64;
constexpr int PIECES = 8;              // vertical strips per batch
constexpr int IROWS  = 32;             // interior rows per strip
constexpr int G      = 16;             // block ghost width = steps per round
constexpr int ROUNDS = NT_ / G;        // 16
constexpr int TR     = 16;             // wave tile rows (8 owned + 4+4 ghost)
constexpr float DT2  = 1e-6f;          // DT*DT
constexpr float KLAP = 1e-8f;          // DT*DT/(DH*DH)
constexpr size_t FLAGS_BYTES = 4096;
constexpr int RCAP = 6;

// DPP lane shifts (R10-verified mapping): wave_shr:1 = lane i <- i-1 (shfl_up),
// wave_shl:1 = lane i <- i+1 (shfl_down). bound_ctrl zeroes edge lanes (cf=0
// boundary cols make those don't-cares).
__device__ __forceinline__ float dpp_up1(float v) {
    return __int_as_float(__builtin_amdgcn_update_dpp(
        0, __float_as_int(v), 0x138, 0xf, 0xf, true));
}
__device__ __forceinline__ float dpp_dn1(float v) {
    return __int_as_float(__builtin_amdgcn_update_dpp(
        0, __float_as_int(v), 0x130, 0xf, 0xf, true));
}

// one barrier-free leapfrog sub-step over tile rows [LO,HI]:
// P[i] <- 2*C[i] - P[i] + cf[i]*lap(C) (+ source). Pure VALU+DPP.
template<int LO, int HI>
__device__ __forceinline__ void substep(v4f (&C)[TR], v4f (&P)[TR],
                                        const v4f (&cf)[TR], float sv,
                                        int si, int sj, bool has_src) {
#pragma unroll
    for (int i = LO; i <= HI; ++i) {
        v4f n = C[i - 1], s = C[i + 1], c = C[i];
        float wv = dpp_up1(c.w);   // col c0-1
        float ev = dpp_dn1(c.x);   // col c0+4
        v4f hn;
        { float sm = (n.x + s.x) + (wv  + c.y);
          hn.x = fmaf(cf[i].x, fmaf(-4.f, c.x, sm), fmaf(2.f, c.x, -P[i].x)); }
        { float sm = (n.y + s.y) + (c.x + c.z);
          hn.y = fmaf(cf[i].y, fmaf(-4.f, c.y, sm), fmaf(2.f, c.y, -P[i].y)); }
        { float sm = (n.z + s.z) + (c.y + c.w);
          hn.z = fmaf(cf[i].z, fmaf(-4.f, c.z, sm), fmaf(2.f, c.z, -P[i].z)); }
        { float sm = (n.w + s.w) + (c.z + ev );
          hn.w = fmaf(cf[i].w, fmaf(-4.f, c.w, sm), fmaf(2.f, c.w, -P[i].w)); }
        if (has_src && si == i) {
            if      (sj == 0) hn.x += sv;
            else if (sj == 1) hn.y += sv;
            else if (sj == 2) hn.z += sv;
            else              hn.w += sv;
        }
        P[i] = hn;
    }
}

// select P[4 + ((pk>>2)&7)][pk&3] via cndmask tree (receiver rows are owned)
__device__ __forceinline__ float sel_rc(const v4f (&P)[TR], int pk) {
    int i = (pk >> 2) & 7, j = pk & 3;
    v4f a0 = (i & 1) ? P[5]  : P[4];
    v4f a1 = (i & 1) ? P[7]  : P[6];
    v4f a2 = (i & 1) ? P[9]  : P[8];
    v4f a3 = (i & 1) ? P[11] : P[10];
    v4f b0 = (i & 2) ? a1 : a0;
    v4f b1 = (i & 2) ? a3 : a2;
    v4f rw = (i & 4) ? b1 : b0;
    float c01 = (j & 1) ? rw.y : rw.x;
    float c23 = (j & 1) ? rw.w : rw.z;
    return (j & 2) ? c23 : c01;
}
} // namespace

// 64 blocks x 512 threads (8 waves): piece p of batch b, blockIdx = p*8 + b.
// Block = 64 ext rows (32 interior + 16 block-ghost each side), exchanged every
// G=16 steps via cached slabs + agent flag handshake (R6/R7/R10-proven).
// NEW (R11): within a block, each wave owns 8 ext rows and keeps a 16-row
// register tile (4 wave-ghost rows each side, both levels). Waves run W=4
// steps barrier-free (shrinking trapezoid 1..14 -> 4..11), then reseed tile
// ghosts from neighbor waves through LDS (2 barriers / 4 steps). This breaks
// R10's per-step lockstep floor (~1.19us/step of convoy+LDS latency).
extern "C" __global__
__attribute__((amdgpu_flat_work_group_size(512, 512), amdgpu_waves_per_eu(2, 2)))
void wave_phase_kernel(const float* __restrict__ x,
                       const float* __restrict__ vp,
                       const int* __restrict__ src_loc,
                       const int* __restrict__ rec_loc,
                       float* __restrict__ out,
                       int* __restrict__ flags,   // [64] monotone round counters
                       float* __restrict__ gbuf)  // [par2][64][side2][lvl2][16][256]
{
    __shared__ __align__(16) float pub[8][16][256];  // 128 KB reseed buffer
    __shared__ __align__(16) float wav[NT_];         // 1 KB wavelet

    const int bid  = blockIdx.x;
    const int b    = bid & 7;
    const int p    = bid >> 3;
    const int blk  = b * PIECES + p;
    const int tid  = threadIdx.x;
    const int band = tid >> 6;             // wave 0..7 -> owned ext rows band*8..+7
    const int lane = tid & 63;
    const int c0   = lane << 2;
    // tile row i -> ext row band*8 - 4 + i -> global row p*32 - 16 + ext
    const int grt  = p * IROWS - G + band * 8 - 4;  // global row of tile row 0

    if (tid < NT_) wav[tid] = x[b * NT_ + tid];

    // cf: zero outside ext window, at Dirichlet boundary, out-of-domain rows/cols
    v4f cf[TR];
#pragma unroll
    for (int i = 0; i < TR; ++i) {
        int er = band * 8 - 4 + i;
        int gr = grt + i;
        int crow = gr < 0 ? 0 : (gr > 255 ? 255 : gr);
        bool rowok = (er >= 0) && (er < 64) && (gr >= 1) && (gr <= 254);
        v4f vv = *(const v4f*)&vp[crow * NX_ + c0];
        float cc[4];
#pragma unroll
        for (int k = 0; k < 4; ++k) {
            int col = c0 + k;
            float vk = (k == 0) ? vv.x : (k == 1) ? vv.y : (k == 2) ? vv.z : vv.w;
            cc[k] = (rowok && col >= 1 && col <= 254) ? vk * vk * KLAP : 0.f;
        }
        cf[i].x = cc[0]; cf[i].y = cc[1]; cf[i].z = cc[2]; cf[i].w = cc[3];
    }

    // source: tile-row index (real ext rows only; ghost replay is consistent)
    const int sz = src_loc[b * 2 + 0], sx = src_loc[b * 2 + 1];
    const int sext = sz - (p * IROWS - G);
    const int si = sext - (band * 8 - 4);
    const int sj = sx - c0;
    const bool has_src = (sext >= 0) && (sext < 64) &&
                         ((unsigned)si < (unsigned)TR) && ((unsigned)sj < 4u);

    // receiver slots: interior owner only; rows land in owned tile rows 4..11
    int rs[RCAP]; int rcnt = 0;
#pragma unroll 1
    for (int r = 0; r < NREC_; ++r) {
        int rz = rec_loc[(b * NREC_ + r) * 2 + 0];
        int rx = rec_loc[(b * NREC_ + r) * 2 + 1];
        int i = rz - grt, j = rx - c0;
        if (rz >= p * IROWS && rz < p * IROWS + IROWS &&
            i >= 4 && i <= 11 && (unsigned)j < 4u) {
            if (rcnt < RCAP) rs[rcnt] = (r << 5) | ((i - 4) << 2) | j;
            ++rcnt;
        }
    }
    if (rcnt > RCAP) rcnt = RCAP;
    float* outb = out + (size_t)b * NT_ * NREC_;

    v4f Ea[TR], Eb[TR];
    {
        v4f z = {0.f, 0.f, 0.f, 0.f};
#pragma unroll
        for (int i = 0; i < TR; ++i) { Ea[i] = z; Eb[i] = z; }
    }

    auto rec_extract = [&](const v4f (&P)[TR], int tt) {
#pragma unroll
        for (int k = 0; k < RCAP; ++k)
            if (rcnt > k) outb[tt * NREC_ + (rs[k] >> 5)] = sel_rc(P, rs[k]);
    };

    // LDS reseed of wave-tile ghosts from neighbor waves (both levels).
    // pub[band][0..7] = cur owned rows, [8..15] = prev owned rows.
    auto reseed = [&]() {
        __syncthreads();                 // WAR: prior phase's reads done
#pragma unroll
        for (int i = 0; i < 8; ++i) {
            *(v4f*)&pub[band][i][c0]     = Ea[4 + i];
            *(v4f*)&pub[band][8 + i][c0] = Eb[4 + i];
        }
        __syncthreads();
        if (band > 0) {
#pragma unroll
            for (int i = 0; i < 4; ++i)  // cur tile 0..3 <- north owned 4..7
                Ea[i] = *(const v4f*)&pub[band - 1][4 + i][c0];
#pragma unroll
            for (int i = 1; i < 4; ++i)  // prev tile 1..3 <- north owned 5..7
                Eb[i] = *(const v4f*)&pub[band - 1][8 + 4 + i][c0];
        } else {
            v4f z = {0.f, 0.f, 0.f, 0.f};
#pragma unroll
            for (int i = 0; i < 4; ++i) { Ea[i] = z; Eb[i] = z; }
        }
        if (band < 7) {
#pragma unroll
            for (int i = 0; i < 4; ++i)  // cur tile 12..15 <- south owned 0..3
                Ea[12 + i] = *(const v4f*)&pub[band + 1][i][c0];
#pragma unroll
            for (int i = 0; i < 3; ++i)  // prev tile 12..14 <- south owned 0..2
                Eb[12 + i] = *(const v4f*)&pub[band + 1][8 + i][c0];
        } else {
            v4f z = {0.f, 0.f, 0.f, 0.f};
#pragma unroll
            for (int i = 0; i < 4; ++i) { Ea[12 + i] = z; if (i < 3) Eb[12 + i] = z; }
        }
    };

    // block-level ghost exchange (identical protocol to R7/R10)
    auto exchange = [&](int e) {
        auto gptr = [&](int bk, int side, int lvl, int rr) -> float* {
            return gbuf + (((((size_t)(e & 1) * 64 + bk) * 2 + side) * 2 + lvl)
                           * 16 + rr) * 256;
        };
        if (band >= 2 && band <= 5) {      // publish interior (ext 16..47)
            int side = (band >= 4) ? 1 : 0;
            int rr0 = (band - (side ? 4 : 2)) * 8;
#pragma unroll
            for (int i = 0; i < 8; ++i) {
                *(v4f*)&gptr(blk, side, 0, rr0 + i)[c0] = Ea[4 + i];
                *(v4f*)&gptr(blk, side, 1, rr0 + i)[c0] = Eb[4 + i];
            }
        }
        __syncthreads();                   // drain stores (vmcnt) for all waves
        if (tid == 0) {
            __builtin_amdgcn_fence(__ATOMIC_RELEASE, "agent");
            __hip_atomic_store(&flags[blk], e + 1, __ATOMIC_RELEASE,
                               __HIP_MEMORY_SCOPE_AGENT);
            if (p > 0)
                while (__hip_atomic_load(&flags[blk - 1], __ATOMIC_ACQUIRE,
                                         __HIP_MEMORY_SCOPE_AGENT) < e + 1)
                    __builtin_amdgcn_s_sleep(8);
            __builtin_amdgcn_fence(__ATOMIC_ACQUIRE, "agent");
        }
        if (tid == 64 && p < PIECES - 1) {
            while (__hip_atomic_load(&flags[blk + 1], __ATOMIC_ACQUIRE,
                                     __HIP_MEMORY_SCOPE_AGENT) < e + 1)
                __builtin_amdgcn_s_sleep(8);
            __builtin_amdgcn_fence(__ATOMIC_ACQUIRE, "agent");
        }
        __syncthreads();
        if (band <= 1 && p > 0) {          // refill owned ext 0..15 from north
            int rr0 = band * 8;
#pragma unroll
            for (int i = 0; i < 8; ++i) {
                Ea[4 + i] = *(const v4f*)&gptr(blk - 1, 1, 0, rr0 + i)[c0];
                Eb[4 + i] = *(const v4f*)&gptr(blk - 1, 1, 1, rr0 + i)[c0];
            }
        }
        if (band >= 6 && p < PIECES - 1) { // refill owned ext 48..63 from south
            int rr0 = (band - 6) * 8;
#pragma unroll
            for (int i = 0; i < 8; ++i) {
                Ea[4 + i] = *(const v4f*)&gptr(blk + 1, 0, 0, rr0 + i)[c0];
                Eb[4 + i] = *(const v4f*)&gptr(blk + 1, 0, 1, rr0 + i)[c0];
            }
        }
    };

    int t = 0;
#pragma unroll 1
    for (int e = 0; e < ROUNDS; ++e) {
#pragma unroll 1
        for (int ph = 0; ph < 4; ++ph) {   // 4 phases x 4 steps = 16 steps
            reseed();
            v4f w4 = *(const v4f*)&wav[t]; // t % 4 == 0
            substep<1, 14>(Ea, Eb, cf, DT2 * w4.x, si, sj, has_src);
            rec_extract(Eb, t + 0);        // Eb = level t+1
            substep<2, 13>(Eb, Ea, cf, DT2 * w4.y, si, sj, has_src);
            rec_extract(Ea, t + 1);
            substep<3, 12>(Ea, Eb, cf, DT2 * w4.z, si, sj, has_src);
            rec_extract(Eb, t + 2);
            substep<4, 11>(Eb, Ea, cf, DT2 * w4.w, si, sj, has_src);
            rec_extract(Ea, t + 3);        // Ea = cur, Eb = prev
            t += 4;
        }
        if (e < ROUNDS - 1) exchange(e);
    }
}

extern "C" void kernel_launch(void* const* d_in, const int* in_sizes, int n_in,
                              void* d_out, int out_size, void* d_ws, size_t ws_size,
                              hipStream_t stream) {
    const float* x   = (const float*)d_in[0];
    const float* vp  = (const float*)d_in[1];
    const int*   src = (const int*)d_in[2];
    const int*   rec = (const int*)d_in[3];
    float*       o   = (float*)d_out;
    int*   flags = (int*)d_ws;
    float* gbuf  = (float*)((char*)d_ws + FLAGS_BYTES);
    (void)hipMemsetAsync(d_ws, 0, FLAGS_BYTES, stream);   // flags must start at 0
    hipLaunchKernelGGL(wave_phase_kernel, dim3(B_ * PIECES), dim3(512), 0, stream,
                       x, vp, src, rec, o, flags, gbuf);
}

// Round 12
// 463.248 us; speedup vs baseline: 1.1404x; 1.1404x over previous
//
#include <hip/hip_runtime.h>

typedef float v4f __attribute__((ext_vector_type(4)));

namespace {
constexpr int B_     = 8;
constexpr int NT_    = 256;
constexpr int NX_    = 256;
constexpr int NREC_  = 64;
constexpr int PIECES = 8;              // vertical strips per batch
constexpr int IROWS  = 32;             // interior rows per strip
constexpr int G      = 16;             // block ghost width = steps per round
constexpr int ROUNDS = NT_ / G;        // 16
constexpr float DT2  = 1e-6f;          // DT*DT
constexpr float KLAP = 1e-8f;          // DT*DT/(DH*DH)
constexpr size_t FLAGS_BYTES = 4096;
constexpr int RCAP = 6;

// DPP lane shifts (R10-verified mapping): wave_shr:1 = lane i <- i-1 (shfl_up),
// wave_shl:1 = lane i <- i+1 (shfl_down). bound_ctrl zeroes edge lanes (cf=0
// boundary cols make those don't-cares).
__device__ __forceinline__ float dpp_up1(float v) {
    return __int_as_float(__builtin_amdgcn_update_dpp(
        0, __float_as_int(v), 0x138, 0xf, 0xf, true));
}
__device__ __forceinline__ float dpp_dn1(float v) {
    return __int_as_float(__builtin_amdgcn_update_dpp(
        0, __float_as_int(v), 0x130, 0xf, 0xf, true));
}

// barrier-free leapfrog sub-step over tile rows [LO,HI]:
// P[i] <- 2*C[i] - P[i] + cf[i]*lap(C) (+ source). Pure VALU+DPP.
template<int LO, int HI>
__device__ __forceinline__ void substep(const v4f (&C)[8], v4f (&P)[8],
                                        const v4f (&cf)[8], float sv,
                                        int si, int sj, bool has_src) {
#pragma unroll
    for (int i = LO; i <= HI; ++i) {
        v4f n = C[i - 1], s = C[i + 1], c = C[i];
        float wv = dpp_up1(c.w);   // col c0-1
        float ev = dpp_dn1(c.x);   // col c0+4
        v4f hn;
        { float sm = (n.x + s.x) + (wv  + c.y);
          hn.x = fmaf(cf[i].x, fmaf(-4.f, c.x, sm), fmaf(2.f, c.x, -P[i].x)); }
        { float sm = (n.y + s.y) + (c.x + c.z);
          hn.y = fmaf(cf[i].y, fmaf(-4.f, c.y, sm), fmaf(2.f, c.y, -P[i].y)); }
        { float sm = (n.z + s.z) + (c.y + c.w);
          hn.z = fmaf(cf[i].z, fmaf(-4.f, c.z, sm), fmaf(2.f, c.z, -P[i].z)); }
        { float sm = (n.w + s.w) + (c.z + ev );
          hn.w = fmaf(cf[i].w, fmaf(-4.f, c.w, sm), fmaf(2.f, c.w, -P[i].w)); }
        if (has_src && si == i) {
            if      (sj == 0) hn.x += sv;
            else if (sj == 1) hn.y += sv;
            else if (sj == 2) hn.z += sv;
            else              hn.w += sv;
        }
        P[i] = hn;
    }
}

// select P[2 + ((pk>>2)&3)][pk&3] (owned rows 2..5) via cndmask tree
__device__ __forceinline__ float sel4(const v4f (&P)[8], int pk) {
    int i = (pk >> 2) & 3, j = pk & 3;
    v4f a0 = (i & 1) ? P[3] : P[2];
    v4f a1 = (i & 1) ? P[5] : P[4];
    v4f rw = (i & 2) ? a1 : a0;
    float c01 = (j & 1) ? rw.y : rw.x;
    float c23 = (j & 1) ? rw.w : rw.z;
    return (j & 2) ? c23 : c01;
}
} // namespace

// 64 blocks x 1024 threads (16 waves): piece p of batch b, blockIdx = p*8 + b.
// Block = 64 ext rows (32 interior + 16 block-ghost/side), exchange every G=16
// steps (proven protocol). NEW (R12): each wave's tile = 8 rows (4 owned +
// 2 wave-ghost/side, both levels = 24 v4f ~115 regs — fits the 128-reg
// envelope R11 violated). Two steps per reseed (trapezoid 1..6 -> 2..5):
// ONE write->barrier->read chain per 2 steps + 1 cheap WAR barrier. Receiver
// values stage to LDS and flush once per round — per-step barriers no longer
// drain global stores.
extern "C" __global__
__attribute__((amdgpu_flat_work_group_size(1024, 1024), amdgpu_waves_per_eu(4, 4)))
void wave_w2_kernel(const float* __restrict__ x,
                    const float* __restrict__ vp,
                    const int* __restrict__ src_loc,
                    const int* __restrict__ rec_loc,
                    float* __restrict__ out,
                    int* __restrict__ flags,   // [64] monotone round counters
                    float* __restrict__ gbuf)  // [par2][64][side2][lvl2][16][256]
{
    __shared__ __align__(16) float pub[16][6][256];  // 96 KB reseed buffer
    __shared__ __align__(16) float wav[NT_];         // 1 KB wavelet
    __shared__ float rstage[16][NREC_];              // 4 KB receiver staging
    __shared__ unsigned char ownflag[NREC_];         // block owns receiver r?

    const int bid  = blockIdx.x;
    const int b    = bid & 7;
    const int p    = bid >> 3;
    const int blk  = b * PIECES + p;
    const int tid  = threadIdx.x;
    const int band = tid >> 6;             // wave 0..15, owns ext rows 4band..+3
    const int lane = tid & 63;
    const int c0   = lane << 2;
    // tile row i <-> ext row 4band-2+i <-> global row p*32-16 + ext
    const int grt  = p * IROWS - G + 4 * band - 2;  // global row of tile row 0

    if (tid < NT_) wav[tid] = x[b * NT_ + tid];
    if (tid < NREC_) {
        int rz = rec_loc[(b * NREC_ + tid) * 2 + 0];
        ownflag[tid] = (rz >= p * IROWS) && (rz < p * IROWS + IROWS);
    }

    // cf: zero outside ext window [0,64), at Dirichlet boundary, OOD rows/cols
    v4f cf[8];
#pragma unroll
    for (int i = 0; i < 8; ++i) {
        int er = 4 * band - 2 + i;
        int gr = grt + i;
        int crow = gr < 0 ? 0 : (gr > 255 ? 255 : gr);
        bool rowok = (er >= 0) && (er < 64) && (gr >= 1) && (gr <= 254);
        v4f vv = *(const v4f*)&vp[crow * NX_ + c0];
        float cc[4];
#pragma unroll
        for (int k = 0; k < 4; ++k) {
            int col = c0 + k;
            float vk = (k == 0) ? vv.x : (k == 1) ? vv.y : (k == 2) ? vv.z : vv.w;
            cc[k] = (rowok && col >= 1 && col <= 254) ? vk * vk * KLAP : 0.f;
        }
        cf[i].x = cc[0]; cf[i].y = cc[1]; cf[i].z = cc[2]; cf[i].w = cc[3];
    }

    // source tile position (ghost-row replay is consistent by construction)
    const int sz = src_loc[b * 2 + 0], sx = src_loc[b * 2 + 1];
    const int si = sz - grt;
    const int sj = sx - c0;
    const bool has_src = ((unsigned)si < 8u) && ((unsigned)sj < 4u);

    // receiver slots: owned rows (tile 2..5) in block interior. pk=(r<<4)|(i-2)<<2|j
    int rs[RCAP]; int rcnt = 0;
#pragma unroll 1
    for (int r = 0; r < NREC_; ++r) {
        int rz = rec_loc[(b * NREC_ + r) * 2 + 0];
        int rx = rec_loc[(b * NREC_ + r) * 2 + 1];
        int i = rz - grt, j = rx - c0;
        if (rz >= p * IROWS && rz < p * IROWS + IROWS &&
            i >= 2 && i <= 5 && (unsigned)j < 4u) {
            if (rcnt < RCAP) rs[rcnt] = (r << 4) | ((i - 2) << 2) | j;
            ++rcnt;
        }
    }
    if (rcnt > RCAP) rcnt = RCAP;
    float* outb = out + (size_t)b * NT_ * NREC_;

    v4f Ea[8], Eb[8];
    {
        v4f z = {0.f, 0.f, 0.f, 0.f};
#pragma unroll
        for (int i = 0; i < 8; ++i) { Ea[i] = z; Eb[i] = z; }
    }

    auto rec_extract = [&](const v4f (&P)[8], int s) {
#pragma unroll
        for (int k = 0; k < RCAP; ++k)
            if (rcnt > k) rstage[s][rs[k] >> 4] = sel4(P, rs[k]);
    };

    // one phase = reseed + 2 barrier-free steps (t even; Ea=cur, Eb=prev)
    auto phase = [&](int t) {
        // publish: rows 0..3 = Ea owned (tile 2..5); 4..5 = Eb tiles 2 and 5
        *(v4f*)&pub[band][0][c0] = Ea[2];
        *(v4f*)&pub[band][1][c0] = Ea[3];
        *(v4f*)&pub[band][2][c0] = Ea[4];
        *(v4f*)&pub[band][3][c0] = Ea[5];
        *(v4f*)&pub[band][4][c0] = Eb[2];
        *(v4f*)&pub[band][5][c0] = Eb[5];
        __syncthreads();
        v4f z = {0.f, 0.f, 0.f, 0.f};
        if (band > 0) {
            Ea[0] = *(const v4f*)&pub[band - 1][2][c0];  // their tile4 = my tile0
            Ea[1] = *(const v4f*)&pub[band - 1][3][c0];  // their tile5 = my tile1
            Eb[1] = *(const v4f*)&pub[band - 1][5][c0];  // prev tile5 = my tile1
        } else { Ea[0] = z; Ea[1] = z; Eb[1] = z; }
        if (band < 15) {
            Ea[6] = *(const v4f*)&pub[band + 1][0][c0];  // their tile2 = my tile6
            Ea[7] = *(const v4f*)&pub[band + 1][1][c0];  // their tile3 = my tile7
            Eb[6] = *(const v4f*)&pub[band + 1][4][c0];  // prev tile2 = my tile6
        } else { Ea[6] = z; Ea[7] = z; Eb[6] = z; }
        float w0 = wav[t], w1 = wav[t + 1];
        __syncthreads();   // WAR guard only (no memory dep beyond the reads)
        substep<1, 6>(Ea, Eb, cf, DT2 * w0, si, sj, has_src);
        rec_extract(Eb, t & 15);           // Eb = level t+1
        substep<2, 5>(Eb, Ea, cf, DT2 * w1, si, sj, has_src);
        rec_extract(Ea, (t + 1) & 15);     // Ea = level t+2 (owned rows)
    };

    // per-round receiver flush (one global store/thread, masked by ownership)
    auto flush = [&](int t0) {
        int s = tid >> 6, r = tid & 63;
        if (ownflag[r]) outb[(t0 + s) * NREC_ + r] = rstage[s][r];
    };

    // block-level ghost exchange (R7/R10-proven protocol) + receiver flush
    auto exchange = [&](int e) {
        auto gptr = [&](int bk, int side, int lvl, int rr) -> float* {
            return gbuf + (((((size_t)(e & 1) * 64 + bk) * 2 + side) * 2 + lvl)
                           * 16 + rr) * 256;
        };
        if (band >= 4 && band < 12) {      // publish interior owned (ext 16..47)
            int side = (band >= 8) ? 1 : 0;
            int rr0 = 4 * band - 16 - (side ? 16 : 0);   // rr of tile row 2
#pragma unroll
            for (int i = 0; i < 4; ++i) {
                *(v4f*)&gptr(blk, side, 0, rr0 + i)[c0] = Ea[2 + i];
                *(v4f*)&gptr(blk, side, 1, rr0 + i)[c0] = Eb[2 + i];
            }
        }
        __syncthreads();                   // rstage visible + slab stores drained
        flush(e * G);                      // overlaps the flag round-trip below
        if (tid == 0) {
            __builtin_amdgcn_fence(__ATOMIC_RELEASE, "agent");
            __hip_atomic_store(&flags[blk], e + 1, __ATOMIC_RELEASE,
                               __HIP_MEMORY_SCOPE_AGENT);
            if (p > 0)
                while (__hip_atomic_load(&flags[blk - 1], __ATOMIC_ACQUIRE,
                                         __HIP_MEMORY_SCOPE_AGENT) < e + 1)
                    __builtin_amdgcn_s_sleep(8);
            __builtin_amdgcn_fence(__ATOMIC_ACQUIRE, "agent");
        }
        if (tid == 64 && p < PIECES - 1) {
            while (__hip_atomic_load(&flags[blk + 1], __ATOMIC_ACQUIRE,
                                     __HIP_MEMORY_SCOPE_AGENT) < e + 1)
                __builtin_amdgcn_s_sleep(8);
            __builtin_amdgcn_fence(__ATOMIC_ACQUIRE, "agent");
        }
        __syncthreads();
        if (band < 4 && p > 0) {           // owned ext 0..15 <- north side1
            int rr0 = 4 * band;
#pragma unroll
            for (int i = 0; i < 4; ++i) {
                Ea[2 + i] = *(const v4f*)&gptr(blk - 1, 1, 0, rr0 + i)[c0];
                Eb[2 + i] = *(const v4f*)&gptr(blk - 1, 1, 1, rr0 + i)[c0];
            }
        }
        if (band >= 12 && p < PIECES - 1) {  // owned ext 48..63 <- south side0
            int rr0 = 4 * band - 48;
#pragma unroll
            for (int i = 0; i < 4; ++i) {
                Ea[2 + i] = *(const v4f*)&gptr(blk + 1, 0, 0, rr0 + i)[c0];
                Eb[2 + i] = *(const v4f*)&gptr(blk + 1, 0, 1, rr0 + i)[c0];
            }
        }
    };

    int t = 0;
#pragma unroll 1
    for (int e = 0; e < ROUNDS; ++e) {
#pragma unroll 1
        for (int ph = 0; ph < G / 2; ++ph) { phase(t); t += 2; }
        if (e < ROUNDS - 1) exchange(e);
    }
    __syncthreads();                       // final-round rstage visible
    flush((ROUNDS - 1) * G);
}

extern "C" void kernel_launch(void* const* d_in, const int* in_sizes, int n_in,
                              void* d_out, int out_size, void* d_ws, size_t ws_size,
                              hipStream_t stream) {
    const float* x   = (const float*)d_in[0];
    const float* vp  = (const float*)d_in[1];
    const int*   src = (const int*)d_in[2];
    const int*   rec = (const int*)d_in[3];
    float*       o   = (float*)d_out;
    int*   flags = (int*)d_ws;
    float* gbuf  = (float*)((char*)d_ws + FLAGS_BYTES);
    (void)hipMemsetAsync(d_ws, 0, FLAGS_BYTES, stream);   // flags must start at 0
    hipLaunchKernelGGL(wave_w2_kernel, dim3(B_ * PIECES), dim3(1024), 0, stream,
                       x, vp, src, rec, o, flags, gbuf);
}